// Round 6
// baseline (888.230 us; speedup 1.0000x reference)
//
#include <hip/hip_runtime.h>

typedef float f2 __attribute__((ext_vector_type(2)));
typedef float f4 __attribute__((ext_vector_type(4)));

#define TT 2048
#define BB 512
#define II 10
#define HH 20

// One wave (64 lanes) per (direction, batch-sample) sequence.
// Gate split across wave halves: lane j (j<20) computes i_j (row j) and
// g_j (row 40+j); lane 32+j computes f_j (row 20+j) and o_j (row 60+j).
// f_j/o_j reach lane j via 2x __shfl (ds_bpermute, proven in R1).
// h broadcast (all lanes need all 20 h) stays as the single LDS round trip.
// x is prefetched 4 steps deep (per-step 40B x-load misses L3 -> ~900cy).
__global__ __launch_bounds__(64) void lstm_bidir(
    const float* __restrict__ x,
    const float* __restrict__ w_ih_f, const float* __restrict__ w_hh_f,
    const float* __restrict__ b_ih_f, const float* __restrict__ b_hh_f,
    const float* __restrict__ w_ih_r, const float* __restrict__ w_hh_r,
    const float* __restrict__ b_ih_r, const float* __restrict__ b_hh_r,
    float* __restrict__ out)
{
    const int lane = threadIdx.x;
    const int blk  = blockIdx.x;
    const int dir  = blk >> 9;     // 0 = forward, 1 = reverse
    const int s    = blk & 511;    // batch sample

    const float* __restrict__ w_ih = dir ? w_ih_r : w_ih_f;
    const float* __restrict__ w_hh = dir ? w_hh_r : w_hh_f;
    const float* __restrict__ b_ih = dir ? b_ih_r : b_ih_f;
    const float* __restrict__ b_hh = dir ? b_hh_r : b_hh_f;

    const int  lj    = lane & 31;
    const int  j     = (lj < HH) ? lj : (HH - 1);   // clamp keeps loads in-bounds
    const bool uhalf = (lane >= 32);
    const bool valid = (lane < HH);                  // low half owns hidden unit j

    const int rA = j + (uhalf ? HH : 0);             // i-row (low) / f-row (high)
    const int rB = j + 2 * HH + (uhalf ? HH : 0);    // g-row (low) / o-row (high)

    // Weight rows in registers as float2 pairs (v_pk_fma_f32).
    f2 whhA[10], whhB[10], wihA[5], wihB[5];
#pragma unroll
    for (int k = 0; k < 10; ++k) {
        whhA[k] = *(const f2*)(w_hh + rA * HH + 2 * k);
        whhB[k] = *(const f2*)(w_hh + rB * HH + 2 * k);
    }
#pragma unroll
    for (int k = 0; k < 5; ++k) {
        wihA[k] = *(const f2*)(w_ih + rA * II + 2 * k);
        wihB[k] = *(const f2*)(w_ih + rB * II + 2 * k);
    }
    const float bsA = b_ih[rA] + b_hh[rA];
    const float bsB = b_ih[rB] + b_hh[rB];

    // B-gate activation: tanh on low half (g), sigmoid on high half (o).
    // act = mB * rcp(1 + exp(knB * v)) + aB
    const float knB = uhalf ? -1.0f : -2.0f;
    const float mB  = uhalf ?  1.0f :  2.0f;
    const float aB  = uhalf ?  0.0f : -1.0f;

    // Shuffle source: low lanes pull from partner lane j+32 (f,o); others self.
    const int src = valid ? (lane + 32) : lane;

    __shared__ f4 hlds[5];   // h[20] broadcast buffer (one sample per block)
    if (valid) ((float*)hlds)[lane] = 0.0f;
    __builtin_amdgcn_wave_barrier();

    const int t0    = dir ? (TT - 1) : 0;
    const int xstep = dir ? -(BB * II) : (BB * II);
    const int ostep = dir ? -(BB * 2 * HH) : (BB * 2 * HH);

    const int xbase = (t0 * BB + s) * II;
    int ooff = (t0 * BB + s) * (2 * HH) + dir * HH + j;

    // ---- prime the 4-deep x pipeline ----
    f2 xb1[5], xb2[5], xb3[5];
    float xpA, xpB;
    {
        f2 x0[5];
#pragma unroll
        for (int k = 0; k < 5; ++k) x0[k]  = *(const f2*)(x + xbase + 2 * k);
#pragma unroll
        for (int k = 0; k < 5; ++k) xb1[k] = *(const f2*)(x + xbase + xstep + 2 * k);
#pragma unroll
        for (int k = 0; k < 5; ++k) xb2[k] = *(const f2*)(x + xbase + 2 * xstep + 2 * k);
#pragma unroll
        for (int k = 0; k < 5; ++k) xb3[k] = *(const f2*)(x + xbase + 3 * xstep + 2 * k);
        f2 pA = {bsA, 0.f}, pB = {bsB, 0.f};
#pragma unroll
        for (int k = 0; k < 5; ++k) { pA += wihA[k] * x0[k]; pB += wihB[k] * x0[k]; }
        xpA = pA[0] + pA[1];
        xpB = pB[0] + pB[1];
    }
    int xoff4 = xbase + 4 * xstep;   // offset of t+4 (first load issued at tt=0)

    // Prime the h broadcast (zeros)
    f4 hb[5];
#pragma unroll
    for (int k = 0; k < 5; ++k) hb[k] = hlds[k];

    float c = 0.0f, h = 0.0f;

#pragma unroll 4
    for (int tt = 0; tt < TT; ++tt) {
        // ---- issue x load for t+4 (max vmcnt slack) ----
        f2 xb4[5];
#pragma unroll
        for (int k = 0; k < 5; ++k) xb4[k] = *(const f2*)(x + xoff4 + 2 * k);
        xoff4 = (tt < TT - 5) ? (xoff4 + xstep) : xoff4;   // clamp: stays in-bounds

        // ---- recurrent dots: 2 gates x 10 pk-FMA, seeded with xproj ----
        f2 aA0 = {xpA, 0.f}, aA1 = {0.f, 0.f};
        f2 aB0 = {xpB, 0.f}, aB1 = {0.f, 0.f};
#pragma unroll
        for (int k = 0; k < 5; ++k) {
            const f4 hv = hb[k];
            f2 lo; lo[0] = hv[0]; lo[1] = hv[1];
            f2 hh2; hh2[0] = hv[2]; hh2[1] = hv[3];
            aA0 += whhA[2 * k]     * lo;
            aA1 += whhA[2 * k + 1] * hh2;
            aB0 += whhB[2 * k]     * lo;
            aB1 += whhB[2 * k + 1] * hh2;
        }
        aA0 += aA1; aB0 += aB1;
        const float vA = aA0[0] + aA0[1];
        const float vB = aB0[0] + aB0[1];

        // ---- activations: A = sigmoid (i/f), B = tanh g (low) / sigmoid o (high)
        const float actA = __builtin_amdgcn_rcpf(1.0f + __expf(-vA));
        const float actB = __builtin_fmaf(mB,
                            __builtin_amdgcn_rcpf(1.0f + __expf(knB * vB)), aB);

        // ---- pull f_j, o_j from partner lane j+32 (ds_bpermute) ----
        const float fj = __shfl(actA, src);
        const float oj = __shfl(actB, src);

        // ---- state update (meaningful on lanes 0..19) ----
        c = __builtin_fmaf(fj, c, actA * actB);          // low: i*g
        const float th = __builtin_fmaf(2.0f,
                          __builtin_amdgcn_rcpf(1.0f + __expf(-2.0f * c)), -1.0f);
        h = oj * th;

        if (valid) {
            ((float*)hlds)[lane] = h;    // wave-local write, no barrier needed
            out[ooff] = h;
        }
        __builtin_amdgcn_wave_barrier();

        // ---- broadcast read for next step (latency filled by xproj below) ----
#pragma unroll
        for (int k = 0; k < 5; ++k) hb[k] = hlds[k];

        // ---- x-projection for step t+1 from xb1 (loaded 3 iters ago) ----
        f2 pA = {bsA, 0.f}, pB = {bsB, 0.f};
#pragma unroll
        for (int k = 0; k < 5; ++k) { pA += wihA[k] * xb1[k]; pB += wihB[k] * xb1[k]; }
        xpA = pA[0] + pA[1];
        xpB = pB[0] + pB[1];

        // ---- rotate the pipeline (renamed away by unroll 4) ----
#pragma unroll
        for (int k = 0; k < 5; ++k) { xb1[k] = xb2[k]; xb2[k] = xb3[k]; xb3[k] = xb4[k]; }

        ooff += ostep;
    }
}

extern "C" void kernel_launch(void* const* d_in, const int* in_sizes, int n_in,
                              void* d_out, int out_size, void* d_ws, size_t ws_size,
                              hipStream_t stream) {
    const float* xp     = (const float*)d_in[0];
    const float* w_ih_f = (const float*)d_in[1];
    const float* w_hh_f = (const float*)d_in[2];
    const float* b_ih_f = (const float*)d_in[3];
    const float* b_hh_f = (const float*)d_in[4];
    const float* w_ih_r = (const float*)d_in[5];
    const float* w_hh_r = (const float*)d_in[6];
    const float* b_ih_r = (const float*)d_in[7];
    const float* b_hh_r = (const float*)d_in[8];
    float* outp = (float*)d_out;

    hipLaunchKernelGGL(lstm_bidir, dim3(1024), dim3(64), 0, stream,
                       xp, w_ih_f, w_hh_f, b_ih_f, b_hh_f,
                       w_ih_r, w_hh_r, b_ih_r, b_hh_r, outp);
}

// Round 7
// 616.439 us; speedup vs baseline: 1.4409x; 1.4409x over previous
//
#include <hip/hip_runtime.h>

typedef float f2 __attribute__((ext_vector_type(2)));
typedef float f4 __attribute__((ext_vector_type(4)));

#define TT 2048
#define BB 512
#define II 10
#define HH 20
#define CH 16                 // consumer steps per barrier
#define RS 32                 // ring slots = 2 chunks (double buffer)
#define NCHUNK (TT / CH)      // 128

// One block = 2 waves per (direction, sample) sequence.
// Wave 0 (consumer): the serial scan. Lane j (j<20) owns hidden unit j and
//   computes all 4 gate recurrent dots; per step its only memory ops are
//   1x ds_read_b128 (precomputed xproj), the h LDS round trip, 1 store.
// Wave 1 (producer): computes xproj[t] = b + W_ih x[t] for all t (pure
//   function of x, runs ahead), writing f4 per unit into a 32-slot LDS ring.
// Double-buffered ring: consumer chunk k reads slots [k*16 .. +15]%32 while
// producer fills [(k+1)*16 .. +15]%32; one __syncthreads per 16 steps.
__global__ __launch_bounds__(128) void lstm_bidir(
    const float* __restrict__ x,
    const float* __restrict__ w_ih_f, const float* __restrict__ w_hh_f,
    const float* __restrict__ b_ih_f, const float* __restrict__ b_hh_f,
    const float* __restrict__ w_ih_r, const float* __restrict__ w_hh_r,
    const float* __restrict__ b_ih_r, const float* __restrict__ b_hh_r,
    float* __restrict__ out)
{
    const int tid  = threadIdx.x;
    const int wid  = tid >> 6;     // 0 = consumer, 1 = producer
    const int lane = tid & 63;
    const int blk  = blockIdx.x;
    const int dir  = blk >> 9;     // 0 = forward, 1 = reverse
    const int s    = blk & 511;    // batch sample

    const float* __restrict__ w_ih = dir ? w_ih_r : w_ih_f;
    const float* __restrict__ w_hh = dir ? w_hh_r : w_hh_f;
    const float* __restrict__ b_ih = dir ? b_ih_r : b_ih_f;
    const float* __restrict__ b_hh = dir ? b_hh_r : b_hh_f;

    const bool valid = (lane < HH);
    const int  j     = valid ? lane : (HH - 1);   // clamp keeps loads in-bounds

    const int t0    = dir ? (TT - 1) : 0;
    const int xstep = dir ? -(BB * II) : (BB * II);
    const int ostep = dir ? -(BB * 2 * HH) : (BB * 2 * HH);
    const int xbase = (t0 * BB + s) * II;

    __shared__ f4 ring[RS][HH];   // xproj ring: [slot][unit] = (i,f,g,o) pre-acts
    __shared__ f4 hlds[5];        // h[20] broadcast buffer

    if (wid == 1) {
        // ---------------- producer wave ----------------
        f2 wih[4][5];
        float bs[4];
#pragma unroll
        for (int g = 0; g < 4; ++g) {
            const int r = g * HH + j;
#pragma unroll
            for (int k = 0; k < 5; ++k) wih[g][k] = *(const f2*)(w_ih + r * II + 2 * k);
            bs[g] = b_ih[r] + b_hh[r];
        }

        auto produce8 = [&](int base) {
            f2 xb[8][5];
            // issue all 40 loads first (~900cy latency amortized over the batch)
#pragma unroll
            for (int i = 0; i < 8; ++i) {
                int u = base + i; if (u > TT - 1) u = TT - 1;   // in-bounds clamp
                const float* px = x + (xbase + u * xstep);
#pragma unroll
                for (int k = 0; k < 5; ++k) xb[i][k] = *(const f2*)(px + 2 * k);
            }
#pragma unroll
            for (int i = 0; i < 8; ++i) {
                const int u = base + i;
                if (u < TT) {
                    f4 xp;
#pragma unroll
                    for (int g = 0; g < 4; ++g) {
                        f2 p = {bs[g], 0.f};
#pragma unroll
                        for (int k = 0; k < 5; ++k) p += wih[g][k] * xb[i][k];
                        xp[g] = p[0] + p[1];
                    }
                    if (valid) ring[u & (RS - 1)][j] = xp;
                }
            }
        };

        produce8(0);              // prefill steps 0..15
        produce8(8);
        for (int chunk = 0; chunk < NCHUNK; ++chunk) {
            __syncthreads();
            const int base = (chunk + 1) * CH;   // fill next chunk's half
            produce8(base);
            produce8(base + 8);
        }
    } else {
        // ---------------- consumer wave (the serial scan) ----------------
        f2 whh[4][10];
#pragma unroll
        for (int g = 0; g < 4; ++g) {
            const int r = g * HH + j;
#pragma unroll
            for (int k = 0; k < 10; ++k) whh[g][k] = *(const f2*)(w_hh + r * HH + 2 * k);
        }

        if (valid) ((float*)hlds)[lane] = 0.0f;
        __builtin_amdgcn_wave_barrier();

        f4 hb[5];
#pragma unroll
        for (int k = 0; k < 5; ++k) hb[k] = hlds[k];

        float c = 0.0f, h = 0.0f;
        int ooff = (t0 * BB + s) * (2 * HH) + dir * HH + j;
        int t = 0;

        for (int chunk = 0; chunk < NCHUNK; ++chunk) {
            __syncthreads();
            f4 xp = ring[t & (RS - 1)][j];   // first step of chunk (slack: once/16)
#pragma unroll
            for (int i = 0; i < CH; ++i, ++t) {
                // ---- recurrent dots: 4 gates x 10 pk-FMA, seeded with xproj ----
                f2 a0[4], a1[4];
#pragma unroll
                for (int g = 0; g < 4; ++g) { a0[g] = f2{xp[g], 0.f}; a1[g] = f2{0.f, 0.f}; }
#pragma unroll
                for (int k = 0; k < 5; ++k) {
                    const f4 hv = hb[k];
                    f2 lo; lo[0] = hv[0]; lo[1] = hv[1];
                    f2 hi; hi[0] = hv[2]; hi[1] = hv[3];
#pragma unroll
                    for (int g = 0; g < 4; ++g) {
                        a0[g] += whh[g][2 * k]     * lo;
                        a1[g] += whh[g][2 * k + 1] * hi;
                    }
                }
                float v[4];
#pragma unroll
                for (int g = 0; g < 4; ++g) {
                    const f2 a = a0[g] + a1[g];
                    v[g] = a[0] + a[1];
                }

                // ---- activations (lane-local, 4 independent chains) ----
                const float ig = __builtin_amdgcn_rcpf(1.0f + __expf(-v[0]));                 // sigmoid i
                const float fg = __builtin_amdgcn_rcpf(1.0f + __expf(-v[1]));                 // sigmoid f
                const float gg = __builtin_fmaf(2.0f,
                                  __builtin_amdgcn_rcpf(1.0f + __expf(-2.0f * v[2])), -1.0f); // tanh g
                const float og = __builtin_amdgcn_rcpf(1.0f + __expf(-v[3]));                 // sigmoid o

                // ---- lane-local state update ----
                c = __builtin_fmaf(fg, c, ig * gg);
                const float th = __builtin_fmaf(2.0f,
                                  __builtin_amdgcn_rcpf(1.0f + __expf(-2.0f * c)), -1.0f);    // tanh c
                h = og * th;

                if (valid) {
                    ((float*)hlds)[lane] = h;    // wave-local write (in-order LDS pipe)
                    out[ooff] = h;
                }
                __builtin_amdgcn_wave_barrier();

                // ---- reads for next step (hb + xp, latency overlaps loop edge) ----
#pragma unroll
                for (int k = 0; k < 5; ++k) hb[k] = hlds[k];
                if (i < CH - 1) xp = ring[(t + 1) & (RS - 1)][j];   // same chunk half: safe
                ooff += ostep;
            }
        }
    }
}

extern "C" void kernel_launch(void* const* d_in, const int* in_sizes, int n_in,
                              void* d_out, int out_size, void* d_ws, size_t ws_size,
                              hipStream_t stream) {
    const float* xp     = (const float*)d_in[0];
    const float* w_ih_f = (const float*)d_in[1];
    const float* w_hh_f = (const float*)d_in[2];
    const float* b_ih_f = (const float*)d_in[3];
    const float* b_hh_f = (const float*)d_in[4];
    const float* w_ih_r = (const float*)d_in[5];
    const float* w_hh_r = (const float*)d_in[6];
    const float* b_ih_r = (const float*)d_in[7];
    const float* b_hh_r = (const float*)d_in[8];
    float* outp = (float*)d_out;

    hipLaunchKernelGGL(lstm_bidir, dim3(1024), dim3(128), 0, stream,
                       xp, w_ih_f, w_hh_f, b_ih_f, b_hh_f,
                       w_ih_r, w_hh_r, b_ih_r, b_hh_r, outp);
}